// Round 6
// baseline (354.820 us; speedup 1.0000x reference)
//
#include <hip/hip_runtime.h>
#include <cstdint>
#include <cstddef>

// ---------------------------------------------------------------------------
// QuantizedLinear: out = x @ W^T + bias (affine-dequant int16-range weights)
// B=8192, IN=4096, OUT=4096. Dequant to bf16 in ws; 256x256 MFMA GEMM.
// R6 = R5 (one barrier per phase, 32 MFMA/phase, counted lgkmcnt(12),
// chunk-XOR swizzle, XCD swizzle, setprio) + TAIL RACE FIX:
// end-of-phase wait = vmcnt(#stages issued THIS phase) (4 or 0), restoring
// the invariant "at barrier(P), all stages from phases < P are complete".
// R5's unconditional vmcnt(4) let half 127's stage float past phase 125
// (which staged nothing) into phase 126's pre-read -> intermittent race.
// ---------------------------------------------------------------------------

#define B_DIM  8192
#define IN_DIM 4096
#define OUT_DIM 4096

typedef short    bf16x8 __attribute__((ext_vector_type(8)));
typedef float    f32x4  __attribute__((ext_vector_type(4)));
typedef uint16_t u16x8  __attribute__((ext_vector_type(8)));

__device__ __forceinline__ uint16_t f2bf(float f) {
  uint32_t u = __builtin_bit_cast(uint32_t, f);
  u += 0x7FFFu + ((u >> 16) & 1u);
  return (uint16_t)(u >> 16);
}

__device__ __forceinline__ void gload_lds16(const void* g, void* l) {
  __builtin_amdgcn_global_load_lds(
      (const __attribute__((address_space(1))) unsigned int*)g,
      (__attribute__((address_space(3))) unsigned int*)l,
      16, 0, 0);
}

// ---------------- prologue: conversions ----------------

__global__ void cvt_x_kernel(const float* __restrict__ x,
                             uint16_t* __restrict__ o) {
  size_t i = (size_t)blockIdx.x * blockDim.x + threadIdx.x;
  const float4* xv = (const float4*)x;
  float4 a = xv[i * 2], b = xv[i * 2 + 1];
  u16x8 r;
  r[0] = f2bf(a.x); r[1] = f2bf(a.y); r[2] = f2bf(a.z); r[3] = f2bf(a.w);
  r[4] = f2bf(b.x); r[5] = f2bf(b.y); r[6] = f2bf(b.z); r[7] = f2bf(b.w);
  ((u16x8*)o)[i] = r;
}

__global__ void cvt_w_kernel(const int* __restrict__ q,
                             uint16_t* __restrict__ o,
                             const float* __restrict__ sp,
                             const float* __restrict__ wminp) {
  size_t i = (size_t)blockIdx.x * blockDim.x + threadIdx.x;
  float s = *sp, wmin = *wminp;
  const int4* qv = (const int4*)q;
  int4 a = qv[i * 2], b = qv[i * 2 + 1];
  u16x8 r;
  r[0] = f2bf(fmaf((float)a.x + 32768.0f, s, wmin));
  r[1] = f2bf(fmaf((float)a.y + 32768.0f, s, wmin));
  r[2] = f2bf(fmaf((float)a.z + 32768.0f, s, wmin));
  r[3] = f2bf(fmaf((float)a.w + 32768.0f, s, wmin));
  r[4] = f2bf(fmaf((float)b.x + 32768.0f, s, wmin));
  r[5] = f2bf(fmaf((float)b.y + 32768.0f, s, wmin));
  r[6] = f2bf(fmaf((float)b.z + 32768.0f, s, wmin));
  r[7] = f2bf(fmaf((float)b.w + 32768.0f, s, wmin));
  ((u16x8*)o)[i] = r;
}

__global__ void cvt_bias_kernel(const int* __restrict__ qb,
                                float* __restrict__ o,
                                const float* __restrict__ bsp,
                                const float* __restrict__ bminp) {
  int i = blockIdx.x * blockDim.x + threadIdx.x;
  if (i < OUT_DIM)
    o[i] = fmaf((float)qb[i] + 32768.0f, *bsp, *bminp);
}

// ---------------- main GEMM ----------------
// Hazard ledger (phase P consumes K-half P from slot P&3):
//   stage half P+3 at P's issue window into slot (P+3)&3
//   pre-read half P+1 at P's issue window (12 ds_read_b128)
//   end-of-phase wait: vmcnt(S_P), S_P = stages issued at P (4 or 0)
//     => at barrier(P), ALL stages from phases < P are complete (tail-safe)
//   RAW stage->read: half H staged P=H-3, complete at barrier(H-2),
//     pre-read at H-1: one full phase margin.
//   RAW read->mfma: lgkmcnt(12) + in-order per-wave DS return => previous
//     phase's 12-read batch complete (no other lgkm ops in loop).
//   WAR read->restage: last reads of slot (P+3)&3 = pre-reads of half P-1
//     at phase P-2, lgkm-confirmed at P-1 before barrier(P-1) < stage at P.

__global__ __launch_bounds__(512, 2) void gemm256_kernel(
    const uint16_t* __restrict__ A, const uint16_t* __restrict__ Bw,
    const float* __restrict__ bias, float* __restrict__ C) {
  __shared__ bf16x8 Asl[4][1024];  // 4 slots x 16 KiB ([256 rows][4 chunks])
  __shared__ bf16x8 Bsl[4][1024];

  const int tid  = threadIdx.x;
  const int wave = tid >> 6;
  const int lane = tid & 63;

  int bid = blockIdx.x;
  int swz = (bid & 7) * 64 + (bid >> 3);   // bijective, nwg=512
  const int bm = swz >> 4;
  const int bn = swz & 15;
  const int M0 = bm * 256, N0 = bn * 256;

  const int wm = wave >> 2, wn = wave & 3;
  const int l15 = lane & 15, l4 = lane >> 4;
  const int swk = l4 ^ ((l15 >> 1) & 3);          // read-side chunk swizzle
  const int aIdx = (wm * 128 + l15) * 4 + swk;    // + 64*i for A row-block i
  const int bIdx = (wn * 64 + l15) * 4 + swk;     // + 64*n for B col-block n

  const int schunk = (lane & 3) ^ ((lane >> 3) & 3);  // source-side swizzle
  const uint16_t* aSrc =
      A + (size_t)(M0 + wave * 16 + (lane >> 2)) * IN_DIM + schunk * 8;
  const uint16_t* bSrc =
      Bw + (size_t)(N0 + wave * 16 + (lane >> 2)) * IN_DIM + schunk * 8;

  f32x4 acc[8][4];
#pragma unroll
  for (int i = 0; i < 8; ++i)
#pragma unroll
    for (int j = 0; j < 4; ++j) acc[i][j] = (f32x4){0.f, 0.f, 0.f, 0.f};

#define STAGE_A(G, j)                                                       \
  gload_lds16(aSrc + (size_t)(j) * 128 * IN_DIM + (size_t)(G) * 32,         \
              (char*)&Asl[(G) & 3][0] + (j) * 8192 + wave * 1024)
#define STAGE_B(G, j)                                                       \
  gload_lds16(bSrc + (size_t)(j) * 128 * IN_DIM + (size_t)(G) * 32,         \
              (char*)&Bsl[(G) & 3][0] + (j) * 8192 + wave * 1024)
#define STAGE_HALF(G)                                                       \
  do { STAGE_A(G, 0); STAGE_A(G, 1); STAGE_B(G, 0); STAGE_B(G, 1); } while (0)

  // prologue: stage halves 0,1,2; vmcnt(4) => halves 0,1 landed; publish
  STAGE_HALF(0); STAGE_HALF(1); STAGE_HALF(2);
  asm volatile("s_waitcnt vmcnt(4)" ::: "memory");
  __builtin_amdgcn_s_barrier();
  __builtin_amdgcn_sched_barrier(0);

  bf16x8 Ac[8], An[8], Bc[4], Bn[4];
  // preload phase-0 operands from slot 0 (12 reads; phase 0 waits lgkmcnt(12))
#pragma unroll
  for (int i = 0; i < 8; ++i) Ac[i] = Asl[0][aIdx + 64 * i];
#pragma unroll
  for (int n = 0; n < 4; ++n) Bc[n] = Bsl[0][bIdx + 64 * n];

  for (int t = 0; t < 64; ++t) {
    const int s1 = (2 * t + 1) & 3, s2 = (2 * t + 2) & 3;
    const int Ga = 2 * t + 3, Gb = 2 * t + 4;
    const bool pa = (Ga < 128), pb = (Gb < 128);

    // ===== phase 0: consume (Ac,Bc) = half 2t; pre-read s1; stage Ga =====
    if (pa) STAGE_HALF(Ga);
#pragma unroll
    for (int i = 0; i < 8; ++i) An[i] = Asl[s1][aIdx + 64 * i];
#pragma unroll
    for (int n = 0; n < 4; ++n) Bn[n] = Bsl[s1][bIdx + 64 * n];
    asm volatile("s_waitcnt lgkmcnt(12)" ::: "memory");
    __builtin_amdgcn_sched_barrier(0);
    __builtin_amdgcn_s_setprio(1);
#pragma unroll
    for (int i = 0; i < 8; ++i)
#pragma unroll
      for (int n = 0; n < 4; ++n)
        acc[i][n] = __builtin_amdgcn_mfma_f32_16x16x32_bf16(Ac[i], Bc[n],
                                                            acc[i][n], 0, 0, 0);
    __builtin_amdgcn_s_setprio(0);
    if (pa) {  // wait = #stages issued THIS phase (tail-race fix)
      asm volatile("s_waitcnt vmcnt(4)" ::: "memory");
    } else {
      asm volatile("s_waitcnt vmcnt(0)" ::: "memory");
    }
    __builtin_amdgcn_s_barrier();
    __builtin_amdgcn_sched_barrier(0);

    // ===== phase 1: consume (An,Bn) = half 2t+1; pre-read s2; stage Gb ====
    if (pb) STAGE_HALF(Gb);
    if (t < 63) {
#pragma unroll
      for (int i = 0; i < 8; ++i) Ac[i] = Asl[s2][aIdx + 64 * i];
#pragma unroll
      for (int n = 0; n < 4; ++n) Bc[n] = Bsl[s2][bIdx + 64 * n];
      asm volatile("s_waitcnt lgkmcnt(12)" ::: "memory");
    } else {
      asm volatile("s_waitcnt lgkmcnt(0)" ::: "memory");
    }
    __builtin_amdgcn_sched_barrier(0);
    __builtin_amdgcn_s_setprio(1);
#pragma unroll
    for (int i = 0; i < 8; ++i)
#pragma unroll
      for (int n = 0; n < 4; ++n)
        acc[i][n] = __builtin_amdgcn_mfma_f32_16x16x32_bf16(An[i], Bn[n],
                                                            acc[i][n], 0, 0, 0);
    __builtin_amdgcn_s_setprio(0);
    if (pb) {  // wait = #stages issued THIS phase (tail-race fix)
      asm volatile("s_waitcnt vmcnt(4)" ::: "memory");
    } else {
      asm volatile("s_waitcnt vmcnt(0)" ::: "memory");
    }
    __builtin_amdgcn_s_barrier();
    __builtin_amdgcn_sched_barrier(0);
  }
#undef STAGE_A
#undef STAGE_B
#undef STAGE_HALF

  // epilogue: C/D frag layout col=lane&15, row=(lane>>4)*4+j
  const int ccol = N0 + wn * 64 + l15;
#pragma unroll
  for (int nf = 0; nf < 4; ++nf) {
    float bv = bias[ccol + nf * 16];
#pragma unroll
    for (int mf = 0; mf < 8; ++mf) {
      const int r0 = M0 + wm * 128 + mf * 16 + l4 * 4;
#pragma unroll
      for (int j = 0; j < 4; ++j)
        C[(size_t)(r0 + j) * OUT_DIM + ccol + nf * 16] = acc[mf][nf][j] + bv;
    }
  }
}

// ---------------- naive fallback (only if ws too small) ----------------
__global__ void naive_ql_kernel(const float* __restrict__ x,
                                const int* __restrict__ qw,
                                const int* __restrict__ qb,
                                const float* sp, const float* wminp,
                                const float* bsp, const float* bminp,
                                float* __restrict__ out) {
  int o = blockIdx.x * blockDim.x + threadIdx.x;
  int b = blockIdx.y;
  float s = *sp, wmin = *wminp;
  const float* xr = x + (size_t)b * IN_DIM;
  const int* wrow = qw + (size_t)o * IN_DIM;
  float acc = 0.f;
  for (int k = 0; k < IN_DIM; ++k)
    acc += xr[k] * fmaf((float)wrow[k] + 32768.0f, s, wmin);
  out[(size_t)b * OUT_DIM + o] =
      acc + fmaf((float)qb[o] + 32768.0f, *bsp, *bminp);
}

// ---------------- launch ----------------
extern "C" void kernel_launch(void* const* d_in, const int* in_sizes, int n_in,
                              void* d_out, int out_size, void* d_ws,
                              size_t ws_size, hipStream_t stream) {
  const float* x      = (const float*)d_in[0];
  const int*   qw     = (const int*)d_in[1];
  const int*   qb     = (const int*)d_in[2];
  const float* scale  = (const float*)d_in[3];
  const float* wmin   = (const float*)d_in[4];
  const float* bscale = (const float*)d_in[5];
  const float* bmin   = (const float*)d_in[6];
  float* out = (float*)d_out;

  const size_t xb_bytes = (size_t)B_DIM * IN_DIM * 2;
  const size_t wb_bytes = (size_t)OUT_DIM * IN_DIM * 2;
  const size_t bias_bytes = (size_t)OUT_DIM * 4;

  if (ws_size < xb_bytes + wb_bytes + bias_bytes) {
    naive_ql_kernel<<<dim3(OUT_DIM / 256, B_DIM), 256, 0, stream>>>(
        x, qw, qb, scale, wmin, bscale, bmin, out);
    return;
  }

  uint16_t* Xb    = (uint16_t*)d_ws;
  uint16_t* Wb    = (uint16_t*)((char*)d_ws + xb_bytes);
  float*    biasf = (float*)((char*)d_ws + xb_bytes + wb_bytes);

  cvt_x_kernel<<<(B_DIM * (size_t)IN_DIM / 8 + 255) / 256, 256, 0, stream>>>(x, Xb);
  cvt_w_kernel<<<(OUT_DIM * (size_t)IN_DIM / 8 + 255) / 256, 256, 0, stream>>>(
      qw, Wb, scale, wmin);
  cvt_bias_kernel<<<(OUT_DIM + 255) / 256, 256, 0, stream>>>(qb, biasf, bscale,
                                                             bmin);

  gemm256_kernel<<<512, 512, 0, stream>>>(Xb, Wb, biasf, out);
}

// Round 7
// 306.653 us; speedup vs baseline: 1.1571x; 1.1571x over previous
//
#include <hip/hip_runtime.h>
#include <cstdint>
#include <cstddef>

// ---------------------------------------------------------------------------
// QuantizedLinear: out = x @ W^T + bias (affine-dequant int16-range weights)
// B=8192, IN=4096, OUT=4096. Dequant to bf16 in ws; 256x256 MFMA GEMM.
// R7: faithful m201 8-phase template port. Phase = (slot, mf-half):
//   [stage 1 half-tile (2 gload) ; ds-read 4 or 8 b128] barrier ; lgkmcnt(0) ;
//   setprio ; 16 MFMA ; setprio ; [vmcnt at odd-phase end] barrier.
// Slots: q0,q1<-slot0, q2,q3<-slot1, q4,q5<-slot2, q6,q7<-slot3 (compile-time).
// Stage map (iter u): q0:A(4u+3)->s3 q1:B(4u+3) q2:A(4u+4)->s0 q3:B(4u+4)
//   q4:A(4u+5)->s1 q5:B(4u+5) q6:A(4u+6)->s2 q7:B(4u+6).
// Ledger: restage slot s at phase q only after s's reads drained (prev phase's
//   lgkmcnt(0), published by its end barrier). vmcnt(4) every odd-phase end
//   (tail u=31: vmcnt(0) where no stages issued) => every half confirmed >=1
//   phase before first read. Prologue: stage h0,h1,h2; vmcnt(8) confirms h0.
// Chunk-XOR LDS swizzle (R3, conflicts=0) + XCD block swizzle unchanged.
// ---------------------------------------------------------------------------

#define B_DIM  8192
#define IN_DIM 4096
#define OUT_DIM 4096

typedef short    bf16x8 __attribute__((ext_vector_type(8)));
typedef float    f32x4  __attribute__((ext_vector_type(4)));
typedef uint16_t u16x8  __attribute__((ext_vector_type(8)));

__device__ __forceinline__ uint16_t f2bf(float f) {
  uint32_t u = __builtin_bit_cast(uint32_t, f);
  u += 0x7FFFu + ((u >> 16) & 1u);
  return (uint16_t)(u >> 16);
}

__device__ __forceinline__ void gload_lds16(const void* g, void* l) {
  __builtin_amdgcn_global_load_lds(
      (const __attribute__((address_space(1))) unsigned int*)g,
      (__attribute__((address_space(3))) unsigned int*)l,
      16, 0, 0);
}

// ---------------- prologue: conversions ----------------

__global__ void cvt_x_kernel(const float* __restrict__ x,
                             uint16_t* __restrict__ o) {
  size_t i = (size_t)blockIdx.x * blockDim.x + threadIdx.x;
  const float4* xv = (const float4*)x;
  float4 a = xv[i * 2], b = xv[i * 2 + 1];
  u16x8 r;
  r[0] = f2bf(a.x); r[1] = f2bf(a.y); r[2] = f2bf(a.z); r[3] = f2bf(a.w);
  r[4] = f2bf(b.x); r[5] = f2bf(b.y); r[6] = f2bf(b.z); r[7] = f2bf(b.w);
  ((u16x8*)o)[i] = r;
}

__global__ void cvt_w_kernel(const int* __restrict__ q,
                             uint16_t* __restrict__ o,
                             const float* __restrict__ sp,
                             const float* __restrict__ wminp) {
  size_t i = (size_t)blockIdx.x * blockDim.x + threadIdx.x;
  float s = *sp, wmin = *wminp;
  const int4* qv = (const int4*)q;
  int4 a = qv[i * 2], b = qv[i * 2 + 1];
  u16x8 r;
  r[0] = f2bf(fmaf((float)a.x + 32768.0f, s, wmin));
  r[1] = f2bf(fmaf((float)a.y + 32768.0f, s, wmin));
  r[2] = f2bf(fmaf((float)a.z + 32768.0f, s, wmin));
  r[3] = f2bf(fmaf((float)a.w + 32768.0f, s, wmin));
  r[4] = f2bf(fmaf((float)b.x + 32768.0f, s, wmin));
  r[5] = f2bf(fmaf((float)b.y + 32768.0f, s, wmin));
  r[6] = f2bf(fmaf((float)b.z + 32768.0f, s, wmin));
  r[7] = f2bf(fmaf((float)b.w + 32768.0f, s, wmin));
  ((u16x8*)o)[i] = r;
}

__global__ void cvt_bias_kernel(const int* __restrict__ qb,
                                float* __restrict__ o,
                                const float* __restrict__ bsp,
                                const float* __restrict__ bminp) {
  int i = blockIdx.x * blockDim.x + threadIdx.x;
  if (i < OUT_DIM)
    o[i] = fmaf((float)qb[i] + 32768.0f, *bsp, *bminp);
}

// ---------------- main GEMM ----------------

__global__ __launch_bounds__(512, 2) void gemm256_kernel(
    const uint16_t* __restrict__ A, const uint16_t* __restrict__ Bw,
    const float* __restrict__ bias, float* __restrict__ C) {
  __shared__ bf16x8 Asl[4][1024];  // 4 slots x 16 KiB ([256 rows][4 chunks])
  __shared__ bf16x8 Bsl[4][1024];

  const int tid  = threadIdx.x;
  const int wave = tid >> 6;
  const int lane = tid & 63;

  int bid = blockIdx.x;
  int swz = (bid & 7) * 64 + (bid >> 3);   // bijective, nwg=512
  const int bm = swz >> 4;
  const int bn = swz & 15;
  const int M0 = bm * 256, N0 = bn * 256;

  const int wm = wave >> 2, wn = wave & 3;
  const int l15 = lane & 15, l4 = lane >> 4;
  const int swk = l4 ^ ((l15 >> 1) & 3);          // read-side chunk swizzle
  const int aIdx = (wm * 128 + l15) * 4 + swk;    // + 64*i for A row-block i
  const int bIdx = (wn * 64 + l15) * 4 + swk;     // + 64*n for B col-block n

  const int schunk = (lane & 3) ^ ((lane >> 3) & 3);  // source-side swizzle
  const uint16_t* aSrc =
      A + (size_t)(M0 + wave * 16 + (lane >> 2)) * IN_DIM + schunk * 8;
  const uint16_t* bSrc =
      Bw + (size_t)(N0 + wave * 16 + (lane >> 2)) * IN_DIM + schunk * 8;

  f32x4 acc[8][4];
#pragma unroll
  for (int i = 0; i < 8; ++i)
#pragma unroll
    for (int j = 0; j < 4; ++j) acc[i][j] = (f32x4){0.f, 0.f, 0.f, 0.f};

#define STAGE_A(G, j)                                                       \
  gload_lds16(aSrc + (size_t)(j) * 128 * IN_DIM + (size_t)(G) * 32,         \
              (char*)&Asl[(G) & 3][0] + (j) * 8192 + wave * 1024)
#define STAGE_B(G, j)                                                       \
  gload_lds16(bSrc + (size_t)(j) * 128 * IN_DIM + (size_t)(G) * 32,         \
              (char*)&Bsl[(G) & 3][0] + (j) * 8192 + wave * 1024)

  // prologue: stage halves 0,1,2 (A+B each, 12 insts); vmcnt(8) => h0 landed
  STAGE_A(0, 0); STAGE_A(0, 1); STAGE_B(0, 0); STAGE_B(0, 1);
  STAGE_A(1, 0); STAGE_A(1, 1); STAGE_B(1, 0); STAGE_B(1, 1);
  STAGE_A(2, 0); STAGE_A(2, 1); STAGE_B(2, 0); STAGE_B(2, 1);
  asm volatile("s_waitcnt vmcnt(8)" ::: "memory");
  __builtin_amdgcn_s_barrier();
  __builtin_amdgcn_sched_barrier(0);

  bf16x8 Af[4], Bf[4];

  // PHASE(slot s, mf-base m0, LOADB, stage statement, end-wait statement)
#define PHASE(s, m0, LOADB, STG, EW)                                        \
  {                                                                         \
    STG;                                                                    \
    if (LOADB) {                                                            \
      _Pragma("unroll")                                                     \
      for (int n = 0; n < 4; ++n) Bf[n] = Bsl[s][bIdx + 64 * n];            \
    }                                                                       \
    _Pragma("unroll")                                                       \
    for (int i = 0; i < 4; ++i) Af[i] = Asl[s][aIdx + 64 * ((m0) + i)];     \
    __builtin_amdgcn_s_barrier();                                           \
    asm volatile("s_waitcnt lgkmcnt(0)" ::: "memory");                      \
    __builtin_amdgcn_sched_barrier(0);                                      \
    __builtin_amdgcn_s_setprio(1);                                          \
    _Pragma("unroll")                                                       \
    for (int i = 0; i < 4; ++i)                                             \
      _Pragma("unroll")                                                     \
      for (int n = 0; n < 4; ++n)                                           \
        acc[(m0) + i][n] = __builtin_amdgcn_mfma_f32_16x16x32_bf16(         \
            Af[i], Bf[n], acc[(m0) + i][n], 0, 0, 0);                       \
    __builtin_amdgcn_s_setprio(0);                                          \
    EW;                                                                     \
    __builtin_amdgcn_s_barrier();                                           \
    __builtin_amdgcn_sched_barrier(0);                                      \
  }

#define VM4 asm volatile("s_waitcnt vmcnt(4)" ::: "memory")
#define VM0 asm volatile("s_waitcnt vmcnt(0)" ::: "memory")
#define NOWAIT ((void)0)

  for (int u = 0; u < 32; ++u) {
    const int G0 = 4 * u + 3, G1 = 4 * u + 4, G2 = 4 * u + 5, G3 = 4 * u + 6;
    const bool p1 = (G1 < 128), p2 = (G2 < 128), p3 = (G3 < 128);

    // q0: slot0, mf 0-3, load B; stage A(G0)->slot3
    PHASE(0, 0, true, { STAGE_A(G0, 0); STAGE_A(G0, 1); }, NOWAIT);
    // q1: slot0, mf 4-7; stage B(G0); vmcnt(4)
    PHASE(0, 4, false, { STAGE_B(G0, 0); STAGE_B(G0, 1); }, VM4);
    // q2: slot1, mf 0-3, load B; stage A(G1)->slot0
    PHASE(1, 0, true, { if (p1) { STAGE_A(G1, 0); STAGE_A(G1, 1); } }, NOWAIT);
    // q3: slot1, mf 4-7; stage B(G1); vmcnt(4 if staged else 0)
    PHASE(1, 4, false, { if (p1) { STAGE_B(G1, 0); STAGE_B(G1, 1); } },
          { if (p1) { VM4; } else { VM0; } });
    // q4: slot2, mf 0-3, load B; stage A(G2)->slot1
    PHASE(2, 0, true, { if (p2) { STAGE_A(G2, 0); STAGE_A(G2, 1); } }, NOWAIT);
    // q5: slot2, mf 4-7; stage B(G2)
    PHASE(2, 4, false, { if (p2) { STAGE_B(G2, 0); STAGE_B(G2, 1); } },
          { if (p2) { VM4; } else { VM0; } });
    // q6: slot3, mf 0-3, load B; stage A(G3)->slot2
    PHASE(3, 0, true, { if (p3) { STAGE_A(G3, 0); STAGE_A(G3, 1); } }, NOWAIT);
    // q7: slot3, mf 4-7; stage B(G3)
    PHASE(3, 4, false, { if (p3) { STAGE_B(G3, 0); STAGE_B(G3, 1); } },
          { if (p3) { VM4; } else { VM0; } });
  }
#undef PHASE
#undef VM4
#undef VM0
#undef NOWAIT
#undef STAGE_A
#undef STAGE_B

  // epilogue: C/D frag layout col=lane&15, row=(lane>>4)*4+j
  const int ccol = N0 + wn * 64 + l15;
#pragma unroll
  for (int nf = 0; nf < 4; ++nf) {
    float bv = bias[ccol + nf * 16];
#pragma unroll
    for (int mf = 0; mf < 8; ++mf) {
      const int r0 = M0 + wm * 128 + mf * 16 + l4 * 4;
#pragma unroll
      for (int j = 0; j < 4; ++j)
        C[(size_t)(r0 + j) * OUT_DIM + ccol + nf * 16] = acc[mf][nf][j] + bv;
    }
  }
}

// ---------------- naive fallback (only if ws too small) ----------------
__global__ void naive_ql_kernel(const float* __restrict__ x,
                                const int* __restrict__ qw,
                                const int* __restrict__ qb,
                                const float* sp, const float* wminp,
                                const float* bsp, const float* bminp,
                                float* __restrict__ out) {
  int o = blockIdx.x * blockDim.x + threadIdx.x;
  int b = blockIdx.y;
  float s = *sp, wmin = *wminp;
  const float* xr = x + (size_t)b * IN_DIM;
  const int* wrow = qw + (size_t)o * IN_DIM;
  float acc = 0.f;
  for (int k = 0; k < IN_DIM; ++k)
    acc += xr[k] * fmaf((float)wrow[k] + 32768.0f, s, wmin);
  out[(size_t)b * OUT_DIM + o] =
      acc + fmaf((float)qb[o] + 32768.0f, *bsp, *bminp);
}

// ---------------- launch ----------------
extern "C" void kernel_launch(void* const* d_in, const int* in_sizes, int n_in,
                              void* d_out, int out_size, void* d_ws,
                              size_t ws_size, hipStream_t stream) {
  const float* x      = (const float*)d_in[0];
  const int*   qw     = (const int*)d_in[1];
  const int*   qb     = (const int*)d_in[2];
  const float* scale  = (const float*)d_in[3];
  const float* wmin   = (const float*)d_in[4];
  const float* bscale = (const float*)d_in[5];
  const float* bmin   = (const float*)d_in[6];
  float* out = (float*)d_out;

  const size_t xb_bytes = (size_t)B_DIM * IN_DIM * 2;
  const size_t wb_bytes = (size_t)OUT_DIM * IN_DIM * 2;
  const size_t bias_bytes = (size_t)OUT_DIM * 4;

  if (ws_size < xb_bytes + wb_bytes + bias_bytes) {
    naive_ql_kernel<<<dim3(OUT_DIM / 256, B_DIM), 256, 0, stream>>>(
        x, qw, qb, scale, wmin, bscale, bmin, out);
    return;
  }

  uint16_t* Xb    = (uint16_t*)d_ws;
  uint16_t* Wb    = (uint16_t*)((char*)d_ws + xb_bytes);
  float*    biasf = (float*)((char*)d_ws + xb_bytes + wb_bytes);

  cvt_x_kernel<<<(B_DIM * (size_t)IN_DIM / 8 + 255) / 256, 256, 0, stream>>>(x, Xb);
  cvt_w_kernel<<<(OUT_DIM * (size_t)IN_DIM / 8 + 255) / 256, 256, 0, stream>>>(
      qw, Wb, scale, wmin);
  cvt_bias_kernel<<<(OUT_DIM + 255) / 256, 256, 0, stream>>>(qb, biasf, bscale,
                                                             bmin);

  gemm256_kernel<<<512, 512, 0, stream>>>(Xb, Wb, biasf, out);
}